// Round 4
// baseline (639.459 us; speedup 1.0000x reference)
//
#include <hip/hip_runtime.h>
#include <hip/hip_bf16.h>
#include <stdint.h>

#define B_ 2
#define N_ 9
#define CB_ 80
#define H_ 120
#define W_ 160
#define D_ 64
#define P_ 80000
#define HW_ (H_*W_)        // 19200
#define NPIX_ (B_*N_*HW_)  // 345600
#define NEG_ (-10000.0f)

static __device__ __forceinline__ float bflo(uint32_t u) {
    return __uint_as_float(u << 16);
}
static __device__ __forceinline__ float bfhi(uint32_t u) {
    return __uint_as_float(u & 0xffff0000u);
}
// RNE float->bf16 bits
static __device__ __forceinline__ uint32_t f2bf_bits(float f) {
    uint32_t u = __float_as_uint(f);
    return (u + 0x7fffu + ((u >> 16) & 1u)) >> 16;
}

// ---------------------------------------------------------------------------
// Kernel 1: key_maps for BOTH blocks, fused.  (unchanged this round)
//   km[pix][d][set] bf16, pix = ((b*9+n)*120+h)*160+w
// ---------------------------------------------------------------------------
__global__ __launch_bounds__(256) void keymap_kernel(
    const float* __restrict__ img,
    const float* __restrict__ Wk1, const float* __restrict__ bk1,
    const float* __restrict__ Wk2, const float* __restrict__ bk2,
    uint32_t* __restrict__ km)   // NPIX_*64 dwords (bf16 pairs)
{
    __shared__ __align__(16) float    a_lds[CB_ * 64];
    __shared__ __align__(16) uint16_t wk_lds[CB_ * 128];
    __shared__ float bias_lds[128];
    const int tid = threadIdx.x;

    for (int idx = tid; idx < CB_ * 128; idx += 256) {
        int c = idx >> 7, j = idx & 127;
        int d = j >> 1, s = j & 1;
        float v = s ? Wk2[d * CB_ + c] : Wk1[d * CB_ + c];
        wk_lds[idx] = (uint16_t)f2bf_bits(v);
    }
    if (tid < 128) {
        int d = tid >> 1, s = tid & 1;
        bias_lds[tid] = s ? bk2[d] : bk1[d];
    }

    const int pix0 = blockIdx.x * 64;
    const int bn   = pix0 / HW_;
    const int hw0  = pix0 - bn * HW_;
    const float* ibase = img + (size_t)bn * CB_ * HW_ + hw0;
    for (int idx = tid; idx < CB_ * 64; idx += 256) {
        int c = idx >> 6, px = idx & 63;
        a_lds[idx] = ibase[c * HW_ + px];
    }
    __syncthreads();

    const int dg = tid & 31;
    const int pg = tid >> 5;
    float acc[8][4];
    {
        float b0 = bias_lds[dg * 4 + 0], b1 = bias_lds[dg * 4 + 1];
        float b2 = bias_lds[dg * 4 + 2], b3 = bias_lds[dg * 4 + 3];
        #pragma unroll
        for (int i = 0; i < 8; i++) {
            acc[i][0] = b0; acc[i][1] = b1; acc[i][2] = b2; acc[i][3] = b3;
        }
    }
    #pragma unroll 4
    for (int c = 0; c < CB_; c++) {
        float4 a0 = *reinterpret_cast<const float4*>(&a_lds[c * 64 + pg * 8]);
        float4 a1 = *reinterpret_cast<const float4*>(&a_lds[c * 64 + pg * 8 + 4]);
        uint2  wv = *reinterpret_cast<const uint2*>(&wk_lds[c * 128 + dg * 4]);
        float w0 = bflo(wv.x), w1 = bfhi(wv.x);
        float w2 = bflo(wv.y), w3 = bfhi(wv.y);
        float av[8] = {a0.x, a0.y, a0.z, a0.w, a1.x, a1.y, a1.z, a1.w};
        #pragma unroll
        for (int i = 0; i < 8; i++) {
            acc[i][0] += av[i] * w0;
            acc[i][1] += av[i] * w1;
            acc[i][2] += av[i] * w2;
            acc[i][3] += av[i] * w3;
        }
    }
    uint2* km2 = reinterpret_cast<uint2*>(km);
    #pragma unroll
    for (int i = 0; i < 8; i++) {
        int pix = pix0 + pg * 8 + i;
        uint2 o;
        o.x = f2bf_bits(acc[i][0]) | (f2bf_bits(acc[i][1]) << 16);
        o.y = f2bf_bits(acc[i][2]) | (f2bf_bits(acc[i][3]) << 16);
        km2[(size_t)pix * 32 + dg] = o;
    }
}

// ---------------------------------------------------------------------------
// Kernel 2: persistent-wave attention.
//  - Wq in LDS as packed bf16, stride 33 dwords -> ~19.3 KB/block
//  - __launch_bounds__(256,8): VGPR<=64 -> 8 blocks/CU resident (100% cap)
//  - per-lane predicated tap loads (R2 form): full ILP across the 9 views
// ---------------------------------------------------------------------------
__global__ __launch_bounds__(256, 8) void attn_kernel(
    const uint32_t* __restrict__ km,
    const int*   __restrict__ coords,
    const float* __restrict__ vfeat,
    const float* __restrict__ proj,
    const float* __restrict__ origins,
    const int*   __restrict__ cmask,
    const float* __restrict__ Wq1, const float* __restrict__ bq1,
    const float* __restrict__ Wq2, const float* __restrict__ bq2,
    float* __restrict__ out)
{
    // packed bf16 Wq: wq_lds[set*2112 + d*33 + i] holds (Wq[d][2i], Wq[d][2i+1])
    __shared__ uint32_t wq_lds[2 * 64 * 33];   // 16.9 KB
    __shared__ __align__(16) float f_lds[4 * 64];
    __shared__ float bq_lds[128];
    __shared__ float proj_lds[B_ * N_ * 12];   // 216
    const int tid = threadIdx.x;

    for (int idx = tid; idx < 4096; idx += 256) {
        int s = idx >> 11;
        int r = idx & 2047;
        int d = r >> 5, i = r & 31;
        const float* Wm = s ? Wq2 : Wq1;
        uint32_t lo = f2bf_bits(Wm[d * 64 + 2 * i]);
        uint32_t hi = f2bf_bits(Wm[d * 64 + 2 * i + 1]);
        wq_lds[s * 2112 + d * 33 + i] = lo | (hi << 16);
    }
    if (tid < 128) bq_lds[tid] = (tid < 64) ? bq1[tid] : bq2[tid - 64];
    if (tid < B_ * N_ * 12) proj_lds[tid] = proj[tid];
    __syncthreads();

    const int lane = tid & 63;
    const int wid  = tid >> 6;
    const int nw   = gridDim.x * 4;

    const float o0x = origins[0], o0y = origins[1], o0z = origins[2];
    const float o1x = origins[3], o1y = origins[4], o1z = origins[5];

    const int4* coords4 = reinterpret_cast<const int4*>(coords);

    int p = blockIdx.x * 4 + wid;
    int4  cv  = coords4[p];
    float vf  = vfeat[(size_t)p * 64 + lane];
    int   cmv = cmask[p];

    while (true) {
        // ---- prefetch next point's scalars ----
        const int pn = p + nw;
        const bool have_next = pn < P_;
        int4 cv_n; float vf_n = 0.f; int cm_n = 0;
        if (have_next) {
            cv_n = coords4[pn];
            vf_n = vfeat[(size_t)pn * 64 + lane];
            cm_n = cmask[pn];
        }

        // ---- projection (lanes 0..8) ----
        const int  bi   = cv.w;
        const float wldx = (float)cv.x * 0.16f + (bi ? o1x : o0x);
        const float wldy = (float)cv.y * 0.16f + (bi ? o1y : o0y);
        const float wldz = (float)cv.z * 0.16f + (bi ? o1z : o0z);
        const bool sel = cmv > 1;

        int packw = -1; float fx = 0.f, fy = 0.f;
        if (lane < N_) {
            const float* Pr = &proj_lds[(bi * N_ + lane) * 12];
            float c0 = Pr[0]*wldx + Pr[1]*wldy + Pr[2]*wldz  + Pr[3];
            float c1 = Pr[4]*wldx + Pr[5]*wldy + Pr[6]*wldz  + Pr[7];
            float c2 = Pr[8]*wldx + Pr[9]*wldy + Pr[10]*wldz + Pr[11];
            float gx = 2.f * (c0 / c2) / (float)(W_ - 1) - 1.f;
            float gy = 2.f * (c1 / c2) / (float)(H_ - 1) - 1.f;
            if (fabsf(gx) <= 1.f && fabsf(gy) <= 1.f && c2 > 0.f) {
                float px = (gx + 1.f) * 0.5f * (float)(W_ - 1);
                float py = (gy + 1.f) * 0.5f * (float)(H_ - 1);
                float x0 = floorf(px), y0 = floorf(py);
                fx = px - x0; fy = py - y0;
                int x0i = (int)x0, y0i = (int)y0;
                int pb = ((bi * N_ + lane) * H_ + y0i) * W_ + x0i;
                packw = pb | ((x0i < W_ - 1) ? (1 << 20) : 0)
                           | ((y0i < H_ - 1) ? (1 << 21) : 0);
            }
        }

        int   pwv[N_];
        float kf1[N_], kf2[N_];
        #pragma unroll
        for (int n = 0; n < N_; n++) pwv[n] = __shfl(packw, n);

        // ---- bilinear sample both key maps (per-lane predicated) ----
        #pragma unroll
        for (int n = 0; n < N_; n++) {
            kf1[n] = 0.f; kf2[n] = 0.f;
            int pw = pwv[n];
            if (pw >= 0) {
                float wx = __shfl(fx, n), wy = __shfl(fy, n);
                int pb  = pw & 0xFFFFF;
                int dxo = (pw & (1 << 20)) ? 64 : 0;
                int dyo = (pw & (1 << 21)) ? (W_ * 64) : 0;
                const uint32_t* kb = km + (size_t)pb * 64 + lane;
                uint32_t u00 = kb[0];
                uint32_t u01 = kb[dxo];          // dxo==0 -> re-read u00 (w=0)
                uint32_t u10 = kb[dyo];
                uint32_t u11 = kb[dyo + dxo];
                float w11 = wx * wy;
                float w01 = wx - w11;
                float w10 = wy - w11;
                float w00 = 1.f - wx - wy + w11;
                kf1[n] = w00*bflo(u00) + w01*bflo(u01) + w10*bflo(u10) + w11*bflo(u11);
                kf2[n] = w00*bfhi(u00) + w01*bfhi(u01) + w10*bfhi(u10) + w11*bfhi(u11);
            }
        }

        // ---- block 1: q1 = Wq1 f + bq1 (bf16 weights) ----
        f_lds[wid * 64 + lane] = vf;
        float q1 = bq_lds[lane];
        {
            const uint32_t* wrow = &wq_lds[lane * 33];
            const float4*   fv   = reinterpret_cast<const float4*>(&f_lds[wid * 64]);
            #pragma unroll
            for (int i = 0; i < 16; i++) {
                uint32_t wa = wrow[2 * i], wb = wrow[2 * i + 1];
                float4 v = fv[i];
                q1 += bflo(wa)*v.x + bfhi(wa)*v.y + bflo(wb)*v.z + bfhi(wb)*v.w;
            }
        }
        q1 *= 0.125f;

        float l1[N_];
        #pragma unroll
        for (int n = 0; n < N_; n++) {
            float t = q1 * kf1[n];
            #pragma unroll
            for (int off = 32; off >= 1; off >>= 1) t += __shfl_xor(t, off);
            l1[n] = (pwv[n] >= 0) ? t : NEG_;
        }
        float mx = l1[0];
        #pragma unroll
        for (int n = 1; n < N_; n++) mx = fmaxf(mx, l1[n]);
        float ssum = 0.f, pr[N_];
        #pragma unroll
        for (int n = 0; n < N_; n++) { pr[n] = __expf(l1[n] - mx); ssum += pr[n]; }
        float inv = 1.f / ssum;
        float y1 = 0.f;
        #pragma unroll
        for (int n = 0; n < N_; n++) y1 += pr[n] * kf1[n];
        y1 *= inv;
        const float fcur = vf + (sel ? y1 : 0.f);

        // ---- block 2 ----
        f_lds[wid * 64 + lane] = fcur;
        float q2 = bq_lds[64 + lane];
        {
            const uint32_t* wrow = &wq_lds[2112 + lane * 33];
            const float4*   fv   = reinterpret_cast<const float4*>(&f_lds[wid * 64]);
            #pragma unroll
            for (int i = 0; i < 16; i++) {
                uint32_t wa = wrow[2 * i], wb = wrow[2 * i + 1];
                float4 v = fv[i];
                q2 += bflo(wa)*v.x + bfhi(wa)*v.y + bflo(wb)*v.z + bfhi(wb)*v.w;
            }
        }
        q2 *= 0.125f;

        float l2[N_];
        #pragma unroll
        for (int n = 0; n < N_; n++) {
            float t = q2 * kf2[n];
            #pragma unroll
            for (int off = 32; off >= 1; off >>= 1) t += __shfl_xor(t, off);
            l2[n] = (pwv[n] >= 0) ? t : NEG_;
        }
        float mx2 = l2[0];
        #pragma unroll
        for (int n = 1; n < N_; n++) mx2 = fmaxf(mx2, l2[n]);
        float ssum2 = 0.f, pr2[N_];
        #pragma unroll
        for (int n = 0; n < N_; n++) { pr2[n] = __expf(l2[n] - mx2); ssum2 += pr2[n]; }
        float inv2 = 1.f / ssum2;
        float y2 = 0.f;
        #pragma unroll
        for (int n = 0; n < N_; n++) y2 += pr2[n] * kf2[n];
        y2 *= inv2;

        out[(size_t)p * 64 + lane] = fcur + (sel ? y2 : 0.f);

        if (!have_next) break;
        p = pn; cv = cv_n; vf = vf_n; cmv = cm_n;
    }
}

extern "C" void kernel_launch(void* const* d_in, const int* in_sizes, int n_in,
                              void* d_out, int out_size, void* d_ws, size_t ws_size,
                              hipStream_t stream) {
    const float* img    = (const float*)d_in[0];
    const int*   coords = (const int*)  d_in[1];
    const float* vf     = (const float*)d_in[2];
    const float* proj   = (const float*)d_in[3];
    const float* org    = (const float*)d_in[4];
    const int*   cm     = (const int*)  d_in[5];
    const float* Wq1    = (const float*)d_in[6];
    const float* bq1    = (const float*)d_in[7];
    const float* Wk1    = (const float*)d_in[8];
    const float* bk1    = (const float*)d_in[9];
    const float* Wq2    = (const float*)d_in[10];
    const float* bq2    = (const float*)d_in[11];
    const float* Wk2    = (const float*)d_in[12];
    const float* bk2    = (const float*)d_in[13];

    uint32_t* km = (uint32_t*)d_ws;   // NPIX_*64 dwords = 88.5 MB
    float*    o  = (float*)d_out;

    keymap_kernel<<<dim3(NPIX_ / 64), dim3(256), 0, stream>>>(img, Wk1, bk1, Wk2, bk2, km);
    attn_kernel<<<dim3(2048), dim3(256), 0, stream>>>(km, coords, vf, proj, org, cm,
                                                      Wq1, bq1, Wq2, bq2, o);
}

// Round 5
// 380.627 us; speedup vs baseline: 1.6800x; 1.6800x over previous
//
#include <hip/hip_runtime.h>
#include <hip/hip_bf16.h>
#include <stdint.h>

#define B_ 2
#define N_ 9
#define CB_ 80
#define H_ 120
#define W_ 160
#define D_ 64
#define P_ 80000
#define HW_ (H_*W_)        // 19200
#define NPIX_ (B_*N_*HW_)  // 345600
#define NEG_ (-10000.0f)

static __device__ __forceinline__ float bflo(uint32_t u) {
    return __uint_as_float(u << 16);
}
static __device__ __forceinline__ float bfhi(uint32_t u) {
    return __uint_as_float(u & 0xffff0000u);
}
// RNE float->bf16 bits
static __device__ __forceinline__ uint32_t f2bf_bits(float f) {
    uint32_t u = __float_as_uint(f);
    return (u + 0x7fffu + ((u >> 16) & 1u)) >> 16;
}

// ---------------------------------------------------------------------------
// Kernel 1: key_maps for BOTH blocks, fused.  (unchanged this round)
//   km[pix][d][set] bf16, pix = ((b*9+n)*120+h)*160+w
// ---------------------------------------------------------------------------
__global__ __launch_bounds__(256) void keymap_kernel(
    const float* __restrict__ img,
    const float* __restrict__ Wk1, const float* __restrict__ bk1,
    const float* __restrict__ Wk2, const float* __restrict__ bk2,
    uint32_t* __restrict__ km)   // NPIX_*64 dwords (bf16 pairs)
{
    __shared__ __align__(16) float    a_lds[CB_ * 64];
    __shared__ __align__(16) uint16_t wk_lds[CB_ * 128];
    __shared__ float bias_lds[128];
    const int tid = threadIdx.x;

    for (int idx = tid; idx < CB_ * 128; idx += 256) {
        int c = idx >> 7, j = idx & 127;
        int d = j >> 1, s = j & 1;
        float v = s ? Wk2[d * CB_ + c] : Wk1[d * CB_ + c];
        wk_lds[idx] = (uint16_t)f2bf_bits(v);
    }
    if (tid < 128) {
        int d = tid >> 1, s = tid & 1;
        bias_lds[tid] = s ? bk2[d] : bk1[d];
    }

    const int pix0 = blockIdx.x * 64;
    const int bn   = pix0 / HW_;
    const int hw0  = pix0 - bn * HW_;
    const float* ibase = img + (size_t)bn * CB_ * HW_ + hw0;
    for (int idx = tid; idx < CB_ * 64; idx += 256) {
        int c = idx >> 6, px = idx & 63;
        a_lds[idx] = ibase[c * HW_ + px];
    }
    __syncthreads();

    const int dg = tid & 31;
    const int pg = tid >> 5;
    float acc[8][4];
    {
        float b0 = bias_lds[dg * 4 + 0], b1 = bias_lds[dg * 4 + 1];
        float b2 = bias_lds[dg * 4 + 2], b3 = bias_lds[dg * 4 + 3];
        #pragma unroll
        for (int i = 0; i < 8; i++) {
            acc[i][0] = b0; acc[i][1] = b1; acc[i][2] = b2; acc[i][3] = b3;
        }
    }
    #pragma unroll 4
    for (int c = 0; c < CB_; c++) {
        float4 a0 = *reinterpret_cast<const float4*>(&a_lds[c * 64 + pg * 8]);
        float4 a1 = *reinterpret_cast<const float4*>(&a_lds[c * 64 + pg * 8 + 4]);
        uint2  wv = *reinterpret_cast<const uint2*>(&wk_lds[c * 128 + dg * 4]);
        float w0 = bflo(wv.x), w1 = bfhi(wv.x);
        float w2 = bflo(wv.y), w3 = bfhi(wv.y);
        float av[8] = {a0.x, a0.y, a0.z, a0.w, a1.x, a1.y, a1.z, a1.w};
        #pragma unroll
        for (int i = 0; i < 8; i++) {
            acc[i][0] += av[i] * w0;
            acc[i][1] += av[i] * w1;
            acc[i][2] += av[i] * w2;
            acc[i][3] += av[i] * w3;
        }
    }
    uint2* km2 = reinterpret_cast<uint2*>(km);
    #pragma unroll
    for (int i = 0; i < 8; i++) {
        int pix = pix0 + pg * 8 + i;
        uint2 o;
        o.x = f2bf_bits(acc[i][0]) | (f2bf_bits(acc[i][1]) << 16);
        o.y = f2bf_bits(acc[i][2]) | (f2bf_bits(acc[i][3]) << 16);
        km2[(size_t)pix * 32 + dg] = o;
    }
}

// ---------------------------------------------------------------------------
// Kernel 2: persistent-wave attention.
//  - Wq in LDS as packed bf16, stride 33 dwords -> ~19.5 KB/block
//  - NO forced wave minimum (R4's (256,8) cap caused VGPR=32 + spills);
//    natural VGPR ~56-72 -> 7-8 blocks/CU by LDS+VGPR
//  - per-lane predicated tap loads (R2 form): full ILP across the 9 views
// ---------------------------------------------------------------------------
__global__ __launch_bounds__(256) void attn_kernel(
    const uint32_t* __restrict__ km,
    const int*   __restrict__ coords,
    const float* __restrict__ vfeat,
    const float* __restrict__ proj,
    const float* __restrict__ origins,
    const int*   __restrict__ cmask,
    const float* __restrict__ Wq1, const float* __restrict__ bq1,
    const float* __restrict__ Wq2, const float* __restrict__ bq2,
    float* __restrict__ out)
{
    // packed bf16 Wq: wq_lds[set*2112 + d*33 + i] holds (Wq[d][2i], Wq[d][2i+1])
    __shared__ uint32_t wq_lds[2 * 64 * 33];   // 16.9 KB
    __shared__ __align__(16) float f_lds[4 * 64];
    __shared__ float bq_lds[128];
    __shared__ float proj_lds[B_ * N_ * 12];   // 216
    const int tid = threadIdx.x;

    for (int idx = tid; idx < 4096; idx += 256) {
        int s = idx >> 11;
        int r = idx & 2047;
        int d = r >> 5, i = r & 31;
        const float* Wm = s ? Wq2 : Wq1;
        uint32_t lo = f2bf_bits(Wm[d * 64 + 2 * i]);
        uint32_t hi = f2bf_bits(Wm[d * 64 + 2 * i + 1]);
        wq_lds[s * 2112 + d * 33 + i] = lo | (hi << 16);
    }
    if (tid < 128) bq_lds[tid] = (tid < 64) ? bq1[tid] : bq2[tid - 64];
    if (tid < B_ * N_ * 12) proj_lds[tid] = proj[tid];
    __syncthreads();

    const int lane = tid & 63;
    const int wid  = tid >> 6;
    const int nw   = gridDim.x * 4;

    const float o0x = origins[0], o0y = origins[1], o0z = origins[2];
    const float o1x = origins[3], o1y = origins[4], o1z = origins[5];

    const int4* coords4 = reinterpret_cast<const int4*>(coords);

    int p = blockIdx.x * 4 + wid;
    int4  cv  = coords4[p];
    float vf  = vfeat[(size_t)p * 64 + lane];
    int   cmv = cmask[p];

    while (true) {
        // ---- prefetch next point's scalars ----
        const int pn = p + nw;
        const bool have_next = pn < P_;
        int4 cv_n; float vf_n = 0.f; int cm_n = 0;
        if (have_next) {
            cv_n = coords4[pn];
            vf_n = vfeat[(size_t)pn * 64 + lane];
            cm_n = cmask[pn];
        }

        // ---- projection (lanes 0..8) ----
        const int  bi   = cv.w;
        const float wldx = (float)cv.x * 0.16f + (bi ? o1x : o0x);
        const float wldy = (float)cv.y * 0.16f + (bi ? o1y : o0y);
        const float wldz = (float)cv.z * 0.16f + (bi ? o1z : o0z);
        const bool sel = cmv > 1;

        int packw = -1; float fx = 0.f, fy = 0.f;
        if (lane < N_) {
            const float* Pr = &proj_lds[(bi * N_ + lane) * 12];
            float c0 = Pr[0]*wldx + Pr[1]*wldy + Pr[2]*wldz  + Pr[3];
            float c1 = Pr[4]*wldx + Pr[5]*wldy + Pr[6]*wldz  + Pr[7];
            float c2 = Pr[8]*wldx + Pr[9]*wldy + Pr[10]*wldz + Pr[11];
            float gx = 2.f * (c0 / c2) / (float)(W_ - 1) - 1.f;
            float gy = 2.f * (c1 / c2) / (float)(H_ - 1) - 1.f;
            if (fabsf(gx) <= 1.f && fabsf(gy) <= 1.f && c2 > 0.f) {
                float px = (gx + 1.f) * 0.5f * (float)(W_ - 1);
                float py = (gy + 1.f) * 0.5f * (float)(H_ - 1);
                float x0 = floorf(px), y0 = floorf(py);
                fx = px - x0; fy = py - y0;
                int x0i = (int)x0, y0i = (int)y0;
                int pb = ((bi * N_ + lane) * H_ + y0i) * W_ + x0i;
                packw = pb | ((x0i < W_ - 1) ? (1 << 20) : 0)
                           | ((y0i < H_ - 1) ? (1 << 21) : 0);
            }
        }

        int   pwv[N_];
        float kf1[N_], kf2[N_];
        #pragma unroll
        for (int n = 0; n < N_; n++) pwv[n] = __shfl(packw, n);

        // ---- bilinear sample both key maps (per-lane predicated) ----
        #pragma unroll
        for (int n = 0; n < N_; n++) {
            kf1[n] = 0.f; kf2[n] = 0.f;
            int pw = pwv[n];
            if (pw >= 0) {
                float wx = __shfl(fx, n), wy = __shfl(fy, n);
                int pb  = pw & 0xFFFFF;
                int dxo = (pw & (1 << 20)) ? 64 : 0;
                int dyo = (pw & (1 << 21)) ? (W_ * 64) : 0;
                const uint32_t* kb = km + (size_t)pb * 64 + lane;
                uint32_t u00 = kb[0];
                uint32_t u01 = kb[dxo];          // dxo==0 -> re-read u00 (w=0)
                uint32_t u10 = kb[dyo];
                uint32_t u11 = kb[dyo + dxo];
                float w11 = wx * wy;
                float w01 = wx - w11;
                float w10 = wy - w11;
                float w00 = 1.f - wx - wy + w11;
                kf1[n] = w00*bflo(u00) + w01*bflo(u01) + w10*bflo(u10) + w11*bflo(u11);
                kf2[n] = w00*bfhi(u00) + w01*bfhi(u01) + w10*bfhi(u10) + w11*bfhi(u11);
            }
        }

        // ---- block 1: q1 = Wq1 f + bq1 (bf16 weights) ----
        f_lds[wid * 64 + lane] = vf;
        float q1 = bq_lds[lane];
        {
            const uint32_t* wrow = &wq_lds[lane * 33];
            const float4*   fv   = reinterpret_cast<const float4*>(&f_lds[wid * 64]);
            #pragma unroll
            for (int i = 0; i < 16; i++) {
                uint32_t wa = wrow[2 * i], wb = wrow[2 * i + 1];
                float4 v = fv[i];
                q1 += bflo(wa)*v.x + bfhi(wa)*v.y + bflo(wb)*v.z + bfhi(wb)*v.w;
            }
        }
        q1 *= 0.125f;

        float l1[N_];
        #pragma unroll
        for (int n = 0; n < N_; n++) {
            float t = q1 * kf1[n];
            #pragma unroll
            for (int off = 32; off >= 1; off >>= 1) t += __shfl_xor(t, off);
            l1[n] = (pwv[n] >= 0) ? t : NEG_;
        }
        float mx = l1[0];
        #pragma unroll
        for (int n = 1; n < N_; n++) mx = fmaxf(mx, l1[n]);
        float ssum = 0.f, pr[N_];
        #pragma unroll
        for (int n = 0; n < N_; n++) { pr[n] = __expf(l1[n] - mx); ssum += pr[n]; }
        float inv = 1.f / ssum;
        float y1 = 0.f;
        #pragma unroll
        for (int n = 0; n < N_; n++) y1 += pr[n] * kf1[n];
        y1 *= inv;
        const float fcur = vf + (sel ? y1 : 0.f);

        // ---- block 2 ----
        f_lds[wid * 64 + lane] = fcur;
        float q2 = bq_lds[64 + lane];
        {
            const uint32_t* wrow = &wq_lds[2112 + lane * 33];
            const float4*   fv   = reinterpret_cast<const float4*>(&f_lds[wid * 64]);
            #pragma unroll
            for (int i = 0; i < 16; i++) {
                uint32_t wa = wrow[2 * i], wb = wrow[2 * i + 1];
                float4 v = fv[i];
                q2 += bflo(wa)*v.x + bfhi(wa)*v.y + bflo(wb)*v.z + bfhi(wb)*v.w;
            }
        }
        q2 *= 0.125f;

        float l2[N_];
        #pragma unroll
        for (int n = 0; n < N_; n++) {
            float t = q2 * kf2[n];
            #pragma unroll
            for (int off = 32; off >= 1; off >>= 1) t += __shfl_xor(t, off);
            l2[n] = (pwv[n] >= 0) ? t : NEG_;
        }
        float mx2 = l2[0];
        #pragma unroll
        for (int n = 1; n < N_; n++) mx2 = fmaxf(mx2, l2[n]);
        float ssum2 = 0.f, pr2[N_];
        #pragma unroll
        for (int n = 0; n < N_; n++) { pr2[n] = __expf(l2[n] - mx2); ssum2 += pr2[n]; }
        float inv2 = 1.f / ssum2;
        float y2 = 0.f;
        #pragma unroll
        for (int n = 0; n < N_; n++) y2 += pr2[n] * kf2[n];
        y2 *= inv2;

        out[(size_t)p * 64 + lane] = fcur + (sel ? y2 : 0.f);

        if (!have_next) break;
        p = pn; cv = cv_n; vf = vf_n; cmv = cm_n;
    }
}

extern "C" void kernel_launch(void* const* d_in, const int* in_sizes, int n_in,
                              void* d_out, int out_size, void* d_ws, size_t ws_size,
                              hipStream_t stream) {
    const float* img    = (const float*)d_in[0];
    const int*   coords = (const int*)  d_in[1];
    const float* vf     = (const float*)d_in[2];
    const float* proj   = (const float*)d_in[3];
    const float* org    = (const float*)d_in[4];
    const int*   cm     = (const int*)  d_in[5];
    const float* Wq1    = (const float*)d_in[6];
    const float* bq1    = (const float*)d_in[7];
    const float* Wk1    = (const float*)d_in[8];
    const float* bk1    = (const float*)d_in[9];
    const float* Wq2    = (const float*)d_in[10];
    const float* bq2    = (const float*)d_in[11];
    const float* Wk2    = (const float*)d_in[12];
    const float* bk2    = (const float*)d_in[13];

    uint32_t* km = (uint32_t*)d_ws;   // NPIX_*64 dwords = 88.5 MB
    float*    o  = (float*)d_out;

    keymap_kernel<<<dim3(NPIX_ / 64), dim3(256), 0, stream>>>(img, Wk1, bk1, Wk2, bk2, km);
    attn_kernel<<<dim3(2048), dim3(256), 0, stream>>>(km, coords, vf, proj, org, cm,
                                                      Wq1, bq1, Wq2, bq2, o);
}

// Round 6
// 333.575 us; speedup vs baseline: 1.9170x; 1.1411x over previous
//
#include <hip/hip_runtime.h>
#include <hip/hip_bf16.h>
#include <stdint.h>

#define B_ 2
#define N_ 9
#define CB_ 80
#define H_ 120
#define W_ 160
#define D_ 64
#define P_ 80000
#define HW_ (H_*W_)        // 19200
#define NPIX_ (B_*N_*HW_)  // 345600
#define NEG_ (-10000.0f)

static __device__ __forceinline__ float bflo(uint32_t u) {
    return __uint_as_float(u << 16);
}
static __device__ __forceinline__ float bfhi(uint32_t u) {
    return __uint_as_float(u & 0xffff0000u);
}
// RNE float->bf16 bits
static __device__ __forceinline__ uint32_t f2bf_bits(float f) {
    uint32_t u = __float_as_uint(f);
    return (u + 0x7fffu + ((u >> 16) & 1u)) >> 16;
}
static __device__ __forceinline__ uint32_t packbf(float a, float b) {
    return f2bf_bits(a) | (f2bf_bits(b) << 16);
}

// ---------------------------------------------------------------------------
// Kernel 1: key_maps for BOTH blocks, fused.
//   km[pix][d] dword = (set1 bf16 lo, set2 bf16 hi), pix-major, 64 dwords/pix
// Retiled: thread = 4 pixels x 8 outputs -> 16B A + 16B W per c-iter for
// 32 FMAs (was 32B+8B=40B for 32) -> LDS-BW bound drops ~20%, wider accesses.
// ---------------------------------------------------------------------------
__global__ __launch_bounds__(256) void keymap_kernel(
    const float* __restrict__ img,
    const float* __restrict__ Wk1, const float* __restrict__ bk1,
    const float* __restrict__ Wk2, const float* __restrict__ bk2,
    uint32_t* __restrict__ km)   // NPIX_*64 dwords (bf16 pairs)
{
    __shared__ __align__(16) float    a_lds[CB_ * 64];
    __shared__ __align__(16) uint16_t wk_lds[CB_ * 128];
    __shared__ float bias_lds[128];
    const int tid = threadIdx.x;

    // stage interleaved weights (bf16): wk_lds[c][j], j=2d+s
    for (int idx = tid; idx < CB_ * 128; idx += 256) {
        int c = idx >> 7, j = idx & 127;
        int d = j >> 1, s = j & 1;
        float v = s ? Wk2[d * CB_ + c] : Wk1[d * CB_ + c];
        wk_lds[idx] = (uint16_t)f2bf_bits(v);
    }
    if (tid < 128) {
        int d = tid >> 1, s = tid & 1;
        bias_lds[tid] = s ? bk2[d] : bk1[d];
    }

    const int pix0 = blockIdx.x * 64;
    const int bn   = pix0 / HW_;
    const int hw0  = pix0 - bn * HW_;
    const float* ibase = img + (size_t)bn * CB_ * HW_ + hw0;
    for (int idx = tid; idx < CB_ * 64; idx += 256) {
        int c = idx >> 6, px = idx & 63;
        a_lds[idx] = ibase[c * HW_ + px];
    }
    __syncthreads();

    const int og = tid & 15;   // output group: j = og*8 .. og*8+7
    const int pg = tid >> 4;   // pixel group: pix0 + pg*4 .. +3
    float acc[4][8];
    {
        #pragma unroll
        for (int k = 0; k < 8; k++) {
            float b = bias_lds[og * 8 + k];
            #pragma unroll
            for (int i = 0; i < 4; i++) acc[i][k] = b;
        }
    }
    #pragma unroll 4
    for (int c = 0; c < CB_; c++) {
        float4 a  = *reinterpret_cast<const float4*>(&a_lds[c * 64 + pg * 4]);
        uint4  wv = *reinterpret_cast<const uint4*>(&wk_lds[c * 128 + og * 8]);
        float w[8] = {bflo(wv.x), bfhi(wv.x), bflo(wv.y), bfhi(wv.y),
                      bflo(wv.z), bfhi(wv.z), bflo(wv.w), bfhi(wv.w)};
        float av[4] = {a.x, a.y, a.z, a.w};
        #pragma unroll
        for (int i = 0; i < 4; i++) {
            #pragma unroll
            for (int k = 0; k < 8; k++) acc[i][k] += av[i] * w[k];
        }
    }
    uint4* km4 = reinterpret_cast<uint4*>(km);   // 16 uint4 per pixel
    #pragma unroll
    for (int i = 0; i < 4; i++) {
        int pix = pix0 + pg * 4 + i;
        uint4 o;
        o.x = packbf(acc[i][0], acc[i][1]);
        o.y = packbf(acc[i][2], acc[i][3]);
        o.z = packbf(acc[i][4], acc[i][5]);
        o.w = packbf(acc[i][6], acc[i][7]);
        km4[(size_t)pix * 16 + og] = o;
    }
}

// ---------------------------------------------------------------------------
// Kernel 2: persistent-wave attention — exact R2 structure (known 220 us,
// VGPR 56): fp32 Wq in LDS stride 66, float2 matvec, per-lane predicated
// taps (full MLP across 9 views), grid 1024, no launch-bounds min.
// ---------------------------------------------------------------------------
__global__ __launch_bounds__(256) void attn_kernel(
    const uint32_t* __restrict__ km,
    const int*   __restrict__ coords,
    const float* __restrict__ vfeat,
    const float* __restrict__ proj,
    const float* __restrict__ origins,
    const int*   __restrict__ cmask,
    const float* __restrict__ Wq1, const float* __restrict__ bq1,
    const float* __restrict__ Wq2, const float* __restrict__ bq2,
    float* __restrict__ out)
{
    __shared__ __align__(16) float wq_lds[2 * 64 * 66];
    __shared__ __align__(16) float f_lds[4 * 64];
    __shared__ float bq_lds[128];
    __shared__ float proj_lds[B_ * N_ * 12];   // 216
    const int tid = threadIdx.x;

    for (int idx = tid; idx < 4096; idx += 256) {
        int d = idx >> 6, c = idx & 63;
        wq_lds[d * 66 + c]           = Wq1[idx];
        wq_lds[64 * 66 + d * 66 + c] = Wq2[idx];
    }
    if (tid < 128) bq_lds[tid] = (tid < 64) ? bq1[tid] : bq2[tid - 64];
    if (tid < B_ * N_ * 12) proj_lds[tid] = proj[tid];
    __syncthreads();

    const int lane = tid & 63;
    const int wid  = tid >> 6;
    const int nw   = gridDim.x * 4;

    const float o0x = origins[0], o0y = origins[1], o0z = origins[2];
    const float o1x = origins[3], o1y = origins[4], o1z = origins[5];

    const int4* coords4 = reinterpret_cast<const int4*>(coords);

    int p = blockIdx.x * 4 + wid;
    int4  cv  = coords4[p];
    float vf  = vfeat[(size_t)p * 64 + lane];
    int   cmv = cmask[p];

    while (true) {
        // ---- prefetch next point's scalars ----
        const int pn = p + nw;
        const bool have_next = pn < P_;
        int4 cv_n; float vf_n = 0.f; int cm_n = 0;
        if (have_next) {
            cv_n = coords4[pn];
            vf_n = vfeat[(size_t)pn * 64 + lane];
            cm_n = cmask[pn];
        }

        // ---- projection (lanes 0..8) ----
        const int  bi   = cv.w;
        const float wldx = (float)cv.x * 0.16f + (bi ? o1x : o0x);
        const float wldy = (float)cv.y * 0.16f + (bi ? o1y : o0y);
        const float wldz = (float)cv.z * 0.16f + (bi ? o1z : o0z);
        const bool sel = cmv > 1;

        int packw = -1; float fx = 0.f, fy = 0.f;
        if (lane < N_) {
            const float* Pr = &proj_lds[(bi * N_ + lane) * 12];
            float c0 = Pr[0]*wldx + Pr[1]*wldy + Pr[2]*wldz  + Pr[3];
            float c1 = Pr[4]*wldx + Pr[5]*wldy + Pr[6]*wldz  + Pr[7];
            float c2 = Pr[8]*wldx + Pr[9]*wldy + Pr[10]*wldz + Pr[11];
            float gx = 2.f * (c0 / c2) / (float)(W_ - 1) - 1.f;
            float gy = 2.f * (c1 / c2) / (float)(H_ - 1) - 1.f;
            if (fabsf(gx) <= 1.f && fabsf(gy) <= 1.f && c2 > 0.f) {
                float px = (gx + 1.f) * 0.5f * (float)(W_ - 1);
                float py = (gy + 1.f) * 0.5f * (float)(H_ - 1);
                float x0 = floorf(px), y0 = floorf(py);
                fx = px - x0; fy = py - y0;
                int x0i = (int)x0, y0i = (int)y0;
                int pb = ((bi * N_ + lane) * H_ + y0i) * W_ + x0i;
                packw = pb | ((x0i < W_ - 1) ? (1 << 20) : 0)
                           | ((y0i < H_ - 1) ? (1 << 21) : 0);
            }
        }

        int   pwv[N_];
        float kf1[N_], kf2[N_];
        #pragma unroll
        for (int n = 0; n < N_; n++) pwv[n] = __shfl(packw, n);

        // ---- bilinear sample both key maps (per-lane predicated) ----
        #pragma unroll
        for (int n = 0; n < N_; n++) {
            kf1[n] = 0.f; kf2[n] = 0.f;
            int pw = pwv[n];
            if (pw >= 0) {
                float wx = __shfl(fx, n), wy = __shfl(fy, n);
                int pb  = pw & 0xFFFFF;
                int dxo = (pw & (1 << 20)) ? 64 : 0;
                int dyo = (pw & (1 << 21)) ? (W_ * 64) : 0;
                const uint32_t* kb = km + (size_t)pb * 64 + lane;
                uint32_t u00 = kb[0];
                uint32_t u01 = kb[dxo];          // dxo==0 -> re-read u00 (w=0)
                uint32_t u10 = kb[dyo];
                uint32_t u11 = kb[dyo + dxo];
                float w11 = wx * wy;
                float w01 = wx - w11;
                float w10 = wy - w11;
                float w00 = 1.f - wx - wy + w11;
                kf1[n] = w00*bflo(u00) + w01*bflo(u01) + w10*bflo(u10) + w11*bflo(u11);
                kf2[n] = w00*bfhi(u00) + w01*bfhi(u01) + w10*bfhi(u10) + w11*bfhi(u11);
            }
        }

        // ---- block 1: q1 = Wq1 f + bq1 ----
        f_lds[wid * 64 + lane] = vf;
        float q1 = bq_lds[lane];
        {
            const float2* wrow = reinterpret_cast<const float2*>(&wq_lds[lane * 66]);
            const float2* fv   = reinterpret_cast<const float2*>(&f_lds[wid * 64]);
            #pragma unroll 8
            for (int cc = 0; cc < 32; cc++) {
                float2 w = wrow[cc]; float2 v = fv[cc];
                q1 += w.x * v.x + w.y * v.y;
            }
        }

        float l1[N_];
        #pragma unroll
        for (int n = 0; n < N_; n++) {
            float t = q1 * kf1[n];
            #pragma unroll
            for (int off = 32; off >= 1; off >>= 1) t += __shfl_xor(t, off);
            l1[n] = (pwv[n] >= 0) ? t * 0.125f : NEG_;
        }
        float mx = l1[0];
        #pragma unroll
        for (int n = 1; n < N_; n++) mx = fmaxf(mx, l1[n]);
        float ssum = 0.f, pr[N_];
        #pragma unroll
        for (int n = 0; n < N_; n++) { pr[n] = __expf(l1[n] - mx); ssum += pr[n]; }
        float inv = 1.f / ssum;
        float y1 = 0.f;
        #pragma unroll
        for (int n = 0; n < N_; n++) y1 += pr[n] * kf1[n];
        y1 *= inv;
        const float fcur = vf + (sel ? y1 : 0.f);

        // ---- block 2 ----
        f_lds[wid * 64 + lane] = fcur;
        float q2 = bq_lds[64 + lane];
        {
            const float2* wrow = reinterpret_cast<const float2*>(&wq_lds[64 * 66 + lane * 66]);
            const float2* fv   = reinterpret_cast<const float2*>(&f_lds[wid * 64]);
            #pragma unroll 8
            for (int cc = 0; cc < 32; cc++) {
                float2 w = wrow[cc]; float2 v = fv[cc];
                q2 += w.x * v.x + w.y * v.y;
            }
        }

        float l2[N_];
        #pragma unroll
        for (int n = 0; n < N_; n++) {
            float t = q2 * kf2[n];
            #pragma unroll
            for (int off = 32; off >= 1; off >>= 1) t += __shfl_xor(t, off);
            l2[n] = (pwv[n] >= 0) ? t * 0.125f : NEG_;
        }
        float mx2 = l2[0];
        #pragma unroll
        for (int n = 1; n < N_; n++) mx2 = fmaxf(mx2, l2[n]);
        float ssum2 = 0.f, pr2[N_];
        #pragma unroll
        for (int n = 0; n < N_; n++) { pr2[n] = __expf(l2[n] - mx2); ssum2 += pr2[n]; }
        float inv2 = 1.f / ssum2;
        float y2 = 0.f;
        #pragma unroll
        for (int n = 0; n < N_; n++) y2 += pr2[n] * kf2[n];
        y2 *= inv2;

        out[(size_t)p * 64 + lane] = fcur + (sel ? y2 : 0.f);

        if (!have_next) break;
        p = pn; cv = cv_n; vf = vf_n; cmv = cm_n;
    }
}

extern "C" void kernel_launch(void* const* d_in, const int* in_sizes, int n_in,
                              void* d_out, int out_size, void* d_ws, size_t ws_size,
                              hipStream_t stream) {
    const float* img    = (const float*)d_in[0];
    const int*   coords = (const int*)  d_in[1];
    const float* vf     = (const float*)d_in[2];
    const float* proj   = (const float*)d_in[3];
    const float* org    = (const float*)d_in[4];
    const int*   cm     = (const int*)  d_in[5];
    const float* Wq1    = (const float*)d_in[6];
    const float* bq1    = (const float*)d_in[7];
    const float* Wk1    = (const float*)d_in[8];
    const float* bk1    = (const float*)d_in[9];
    const float* Wq2    = (const float*)d_in[10];
    const float* bq2    = (const float*)d_in[11];
    const float* Wk2    = (const float*)d_in[12];
    const float* bk2    = (const float*)d_in[13];

    uint32_t* km = (uint32_t*)d_ws;   // NPIX_*64 dwords = 88.5 MB
    float*    o  = (float*)d_out;

    keymap_kernel<<<dim3(NPIX_ / 64), dim3(256), 0, stream>>>(img, Wk1, bk1, Wk2, bk2, km);
    attn_kernel<<<dim3(1024), dim3(256), 0, stream>>>(km, coords, vf, proj, org, cm,
                                                      Wq1, bq1, Wq2, bq2, o);
}

// Round 7
// 269.334 us; speedup vs baseline: 2.3742x; 1.2385x over previous
//
#include <hip/hip_runtime.h>
#include <hip/hip_bf16.h>
#include <stdint.h>

#define B_ 2
#define N_ 9
#define CB_ 80
#define H_ 120
#define W_ 160
#define D_ 64
#define P_ 80000
#define HW_ (H_*W_)        // 19200
#define NPIX_ (B_*N_*HW_)  // 345600
#define NEG_ (-10000.0f)

static __device__ __forceinline__ float bflo(uint32_t u) {
    return __uint_as_float(u << 16);
}
static __device__ __forceinline__ float bfhi(uint32_t u) {
    return __uint_as_float(u & 0xffff0000u);
}
// RNE float->bf16 bits
static __device__ __forceinline__ uint32_t f2bf_bits(float f) {
    uint32_t u = __float_as_uint(f);
    return (u + 0x7fffu + ((u >> 16) & 1u)) >> 16;
}
static __device__ __forceinline__ uint32_t packbf(float a, float b) {
    return f2bf_bits(a) | (f2bf_bits(b) << 16);
}

// ---------------------------------------------------------------------------
// Kernel 1: key_maps for BOTH blocks, fused.  (unchanged)
//   km[pix][d] dword = (set1 bf16 lo, set2 bf16 hi), pix-major, 64 dwords/pix
// ---------------------------------------------------------------------------
__global__ __launch_bounds__(256) void keymap_kernel(
    const float* __restrict__ img,
    const float* __restrict__ Wk1, const float* __restrict__ bk1,
    const float* __restrict__ Wk2, const float* __restrict__ bk2,
    uint32_t* __restrict__ km)   // NPIX_*64 dwords (bf16 pairs)
{
    __shared__ __align__(16) float    a_lds[CB_ * 64];
    __shared__ __align__(16) uint16_t wk_lds[CB_ * 128];
    __shared__ float bias_lds[128];
    const int tid = threadIdx.x;

    for (int idx = tid; idx < CB_ * 128; idx += 256) {
        int c = idx >> 7, j = idx & 127;
        int d = j >> 1, s = j & 1;
        float v = s ? Wk2[d * CB_ + c] : Wk1[d * CB_ + c];
        wk_lds[idx] = (uint16_t)f2bf_bits(v);
    }
    if (tid < 128) {
        int d = tid >> 1, s = tid & 1;
        bias_lds[tid] = s ? bk2[d] : bk1[d];
    }

    const int pix0 = blockIdx.x * 64;
    const int bn   = pix0 / HW_;
    const int hw0  = pix0 - bn * HW_;
    const float* ibase = img + (size_t)bn * CB_ * HW_ + hw0;
    for (int idx = tid; idx < CB_ * 64; idx += 256) {
        int c = idx >> 6, px = idx & 63;
        a_lds[idx] = ibase[c * HW_ + px];
    }
    __syncthreads();

    const int og = tid & 15;   // output group: j = og*8 .. og*8+7
    const int pg = tid >> 4;   // pixel group: pix0 + pg*4 .. +3
    float acc[4][8];
    {
        #pragma unroll
        for (int k = 0; k < 8; k++) {
            float b = bias_lds[og * 8 + k];
            #pragma unroll
            for (int i = 0; i < 4; i++) acc[i][k] = b;
        }
    }
    #pragma unroll 4
    for (int c = 0; c < CB_; c++) {
        float4 a  = *reinterpret_cast<const float4*>(&a_lds[c * 64 + pg * 4]);
        uint4  wv = *reinterpret_cast<const uint4*>(&wk_lds[c * 128 + og * 8]);
        float w[8] = {bflo(wv.x), bfhi(wv.x), bflo(wv.y), bfhi(wv.y),
                      bflo(wv.z), bfhi(wv.z), bflo(wv.w), bfhi(wv.w)};
        float av[4] = {a.x, a.y, a.z, a.w};
        #pragma unroll
        for (int i = 0; i < 4; i++) {
            #pragma unroll
            for (int k = 0; k < 8; k++) acc[i][k] += av[i] * w[k];
        }
    }
    uint4* km4 = reinterpret_cast<uint4*>(km);   // 16 uint4 per pixel
    #pragma unroll
    for (int i = 0; i < 4; i++) {
        int pix = pix0 + pg * 4 + i;
        uint4 o;
        o.x = packbf(acc[i][0], acc[i][1]);
        o.y = packbf(acc[i][2], acc[i][3]);
        o.z = packbf(acc[i][4], acc[i][5]);
        o.w = packbf(acc[i][6], acc[i][7]);
        km4[(size_t)pix * 16 + og] = o;
    }
}

// ---------------------------------------------------------------------------
// Kernel 1b: q1 prepass + out-init.
//   q1s[p][d] = 0.125 * (Wq1 . vf[p] + bq1)   (scaled; fp32)
//   out[p]    = vf[p]                          (identity for non-sel points)
// Tile: 64 points x 64 dims per block; thread = 1 point x 16 dims.
// ---------------------------------------------------------------------------
__global__ __launch_bounds__(256) void qinit_kernel(
    const float* __restrict__ vfeat,
    const float* __restrict__ Wq1, const float* __restrict__ bq1,
    float* __restrict__ q1s, float* __restrict__ out)
{
    __shared__ float wt_lds[64][68];   // wt[c][d] = Wq1[d][c], padded
    __shared__ float vf_lds[64][68];
    __shared__ float bq_lds[64];
    const int tid = threadIdx.x;

    for (int idx = tid; idx < 4096; idx += 256) {
        int d = idx >> 6, c = idx & 63;
        wt_lds[c][d] = Wq1[idx];
    }
    if (tid < 64) bq_lds[tid] = bq1[tid];

    const int pt0 = blockIdx.x * 64;
    const float4* vf4 = reinterpret_cast<const float4*>(vfeat + (size_t)pt0 * 64);
    float4* out4 = reinterpret_cast<float4*>(out + (size_t)pt0 * 64);
    for (int idx = tid; idx < 1024; idx += 256) {
        float4 v = vf4[idx];
        out4[idx] = v;                       // out = vf (identity init)
        int r = idx >> 4, c4 = (idx & 15) * 4;
        *reinterpret_cast<float4*>(&vf_lds[r][c4]) = v;
    }
    __syncthreads();

    const int pl = tid >> 2;          // point 0..63
    const int d0 = (tid & 3) * 16;    // dims d0..d0+15
    float acc[16];
    #pragma unroll
    for (int i = 0; i < 16; i++) acc[i] = bq_lds[d0 + i];
    for (int k = 0; k < 64; k++) {
        float a = vf_lds[pl][k];
        const float4* wr = reinterpret_cast<const float4*>(&wt_lds[k][d0]);
        float4 w0 = wr[0], w1 = wr[1], w2 = wr[2], w3 = wr[3];
        acc[0]  += a * w0.x; acc[1]  += a * w0.y; acc[2]  += a * w0.z; acc[3]  += a * w0.w;
        acc[4]  += a * w1.x; acc[5]  += a * w1.y; acc[6]  += a * w1.z; acc[7]  += a * w1.w;
        acc[8]  += a * w2.x; acc[9]  += a * w2.y; acc[10] += a * w2.z; acc[11] += a * w2.w;
        acc[12] += a * w3.x; acc[13] += a * w3.y; acc[14] += a * w3.z; acc[15] += a * w3.w;
    }
    float4* q4 = reinterpret_cast<float4*>(q1s + (size_t)(pt0 + pl) * 64 + d0);
    #pragma unroll
    for (int j = 0; j < 4; j++) {
        q4[j] = make_float4(acc[4*j] * 0.125f, acc[4*j+1] * 0.125f,
                            acc[4*j+2] * 0.125f, acc[4*j+3] * 0.125f);
    }
}

// ---------------------------------------------------------------------------
// Kernel 2: persistent-wave attention, SEL-ONLY (50% of points).
//  - non-sel points: out already = vf (qinit); wave-uniform skip
//  - q1 precomputed (qinit) -> only ONE matvec (Wq2) in-kernel
//  - LDS ~19 KB -> 8 blocks/CU; grid 2048
// ---------------------------------------------------------------------------
__global__ __launch_bounds__(256) void attn_kernel(
    const uint32_t* __restrict__ km,
    const int*   __restrict__ coords,
    const float* __restrict__ vfeat,
    const float* __restrict__ proj,
    const float* __restrict__ origins,
    const int*   __restrict__ cmask,
    const float* __restrict__ q1s,
    const float* __restrict__ Wq2, const float* __restrict__ bq2,
    float* __restrict__ out)
{
    __shared__ __align__(16) float wq_lds[64 * 66];
    __shared__ __align__(16) float f_lds[4 * 64];
    __shared__ float bq_lds[64];
    __shared__ float proj_lds[B_ * N_ * 12];   // 216
    const int tid = threadIdx.x;

    for (int idx = tid; idx < 4096; idx += 256) {
        int d = idx >> 6, c = idx & 63;
        wq_lds[d * 66 + c] = Wq2[idx];
    }
    if (tid < 64) bq_lds[tid] = bq2[tid];
    if (tid < B_ * N_ * 12) proj_lds[tid] = proj[tid];
    __syncthreads();

    const int lane = tid & 63;
    const int wid  = tid >> 6;
    const int nw   = gridDim.x * 4;

    const float o0x = origins[0], o0y = origins[1], o0z = origins[2];
    const float o1x = origins[3], o1y = origins[4], o1z = origins[5];

    const int4* coords4 = reinterpret_cast<const int4*>(coords);

    int p = blockIdx.x * 4 + wid;
    int4 cv  = coords4[p];
    int  cmv = cmask[p];

    while (true) {
        const int pn = p + nw;
        const bool have_next = pn < P_;
        int4 cv_n; int cm_n = 0;
        if (have_next) {
            cv_n = coords4[pn];
            cm_n = cmask[pn];
        }

        if (cmv > 1) {   // wave-uniform: 50% of points do any work at all
            // issue per-lane loads early; consumed late (after taps)
            const float vf = vfeat[(size_t)p * 64 + lane];
            const float q1 = q1s[(size_t)p * 64 + lane];   // pre-scaled

            // ---- projection (lanes 0..8) ----
            const int  bi   = cv.w;
            const float wldx = (float)cv.x * 0.16f + (bi ? o1x : o0x);
            const float wldy = (float)cv.y * 0.16f + (bi ? o1y : o0y);
            const float wldz = (float)cv.z * 0.16f + (bi ? o1z : o0z);

            int packw = -1; float fx = 0.f, fy = 0.f;
            if (lane < N_) {
                const float* Pr = &proj_lds[(bi * N_ + lane) * 12];
                float c0 = Pr[0]*wldx + Pr[1]*wldy + Pr[2]*wldz  + Pr[3];
                float c1 = Pr[4]*wldx + Pr[5]*wldy + Pr[6]*wldz  + Pr[7];
                float c2 = Pr[8]*wldx + Pr[9]*wldy + Pr[10]*wldz + Pr[11];
                float gx = 2.f * (c0 / c2) / (float)(W_ - 1) - 1.f;
                float gy = 2.f * (c1 / c2) / (float)(H_ - 1) - 1.f;
                if (fabsf(gx) <= 1.f && fabsf(gy) <= 1.f && c2 > 0.f) {
                    float px = (gx + 1.f) * 0.5f * (float)(W_ - 1);
                    float py = (gy + 1.f) * 0.5f * (float)(H_ - 1);
                    float x0 = floorf(px), y0 = floorf(py);
                    fx = px - x0; fy = py - y0;
                    int x0i = (int)x0, y0i = (int)y0;
                    int pb = ((bi * N_ + lane) * H_ + y0i) * W_ + x0i;
                    packw = pb | ((x0i < W_ - 1) ? (1 << 20) : 0)
                               | ((y0i < H_ - 1) ? (1 << 21) : 0);
                }
            }

            int   pwv[N_];
            float kf1[N_], kf2[N_];
            #pragma unroll
            for (int n = 0; n < N_; n++) pwv[n] = __shfl(packw, n);

            // ---- bilinear sample both key maps (per-lane predicated) ----
            #pragma unroll
            for (int n = 0; n < N_; n++) {
                kf1[n] = 0.f; kf2[n] = 0.f;
                int pw = pwv[n];
                if (pw >= 0) {
                    float wx = __shfl(fx, n), wy = __shfl(fy, n);
                    int pb  = pw & 0xFFFFF;
                    int dxo = (pw & (1 << 20)) ? 64 : 0;
                    int dyo = (pw & (1 << 21)) ? (W_ * 64) : 0;
                    const uint32_t* kb = km + (size_t)pb * 64 + lane;
                    uint32_t u00 = kb[0];
                    uint32_t u01 = kb[dxo];
                    uint32_t u10 = kb[dyo];
                    uint32_t u11 = kb[dyo + dxo];
                    float w11 = wx * wy;
                    float w01 = wx - w11;
                    float w10 = wy - w11;
                    float w00 = 1.f - wx - wy + w11;
                    kf1[n] = w00*bflo(u00) + w01*bflo(u01) + w10*bflo(u10) + w11*bflo(u11);
                    kf2[n] = w00*bfhi(u00) + w01*bfhi(u01) + w10*bfhi(u10) + w11*bfhi(u11);
                }
            }

            // ---- block 1: logits from precomputed q1 ----
            float l1[N_];
            #pragma unroll
            for (int n = 0; n < N_; n++) {
                float t = q1 * kf1[n];
                #pragma unroll
                for (int off = 32; off >= 1; off >>= 1) t += __shfl_xor(t, off);
                l1[n] = (pwv[n] >= 0) ? t : NEG_;
            }
            float mx = l1[0];
            #pragma unroll
            for (int n = 1; n < N_; n++) mx = fmaxf(mx, l1[n]);
            float ssum = 0.f, pr[N_];
            #pragma unroll
            for (int n = 0; n < N_; n++) { pr[n] = __expf(l1[n] - mx); ssum += pr[n]; }
            float inv = 1.f / ssum;
            float y1 = 0.f;
            #pragma unroll
            for (int n = 0; n < N_; n++) y1 += pr[n] * kf1[n];
            const float fcur = vf + y1 * inv;

            // ---- block 2: q2 = Wq2 fcur + bq2 ----
            f_lds[wid * 64 + lane] = fcur;
            float q2 = bq_lds[lane];
            {
                const float2* wrow = reinterpret_cast<const float2*>(&wq_lds[lane * 66]);
                const float2* fv   = reinterpret_cast<const float2*>(&f_lds[wid * 64]);
                #pragma unroll 8
                for (int cc = 0; cc < 32; cc++) {
                    float2 w = wrow[cc]; float2 v = fv[cc];
                    q2 += w.x * v.x + w.y * v.y;
                }
            }
            q2 *= 0.125f;

            float l2[N_];
            #pragma unroll
            for (int n = 0; n < N_; n++) {
                float t = q2 * kf2[n];
                #pragma unroll
                for (int off = 32; off >= 1; off >>= 1) t += __shfl_xor(t, off);
                l2[n] = (pwv[n] >= 0) ? t : NEG_;
            }
            float mx2 = l2[0];
            #pragma unroll
            for (int n = 1; n < N_; n++) mx2 = fmaxf(mx2, l2[n]);
            float ssum2 = 0.f, pr2[N_];
            #pragma unroll
            for (int n = 0; n < N_; n++) { pr2[n] = __expf(l2[n] - mx2); ssum2 += pr2[n]; }
            float inv2 = 1.f / ssum2;
            float y2 = 0.f;
            #pragma unroll
            for (int n = 0; n < N_; n++) y2 += pr2[n] * kf2[n];

            out[(size_t)p * 64 + lane] = fcur + y2 * inv2;
        }

        if (!have_next) break;
        p = pn; cv = cv_n; cmv = cm_n;
    }
}

extern "C" void kernel_launch(void* const* d_in, const int* in_sizes, int n_in,
                              void* d_out, int out_size, void* d_ws, size_t ws_size,
                              hipStream_t stream) {
    const float* img    = (const float*)d_in[0];
    const int*   coords = (const int*)  d_in[1];
    const float* vf     = (const float*)d_in[2];
    const float* proj   = (const float*)d_in[3];
    const float* org    = (const float*)d_in[4];
    const int*   cm     = (const int*)  d_in[5];
    const float* Wq1    = (const float*)d_in[6];
    const float* bq1    = (const float*)d_in[7];
    const float* Wk1    = (const float*)d_in[8];
    const float* bk1    = (const float*)d_in[9];
    const float* Wq2    = (const float*)d_in[10];
    const float* bq2    = (const float*)d_in[11];
    const float* Wk2    = (const float*)d_in[12];
    const float* bk2    = (const float*)d_in[13];

    uint32_t* km  = (uint32_t*)d_ws;                         // 88.5 MB
    float*    q1s = (float*)((char*)d_ws + (size_t)NPIX_ * 64 * 4); // 20.5 MB
    float*    o   = (float*)d_out;

    keymap_kernel<<<dim3(NPIX_ / 64), dim3(256), 0, stream>>>(img, Wk1, bk1, Wk2, bk2, km);
    qinit_kernel<<<dim3(P_ / 64), dim3(256), 0, stream>>>(vf, Wq1, bq1, q1s, o);
    attn_kernel<<<dim3(2048), dim3(256), 0, stream>>>(km, coords, vf, proj, org, cm,
                                                      q1s, Wq2, bq2, o);
}

// Round 8
// 229.860 us; speedup vs baseline: 2.7820x; 1.1717x over previous
//
#include <hip/hip_runtime.h>
#include <hip/hip_bf16.h>
#include <stdint.h>

#define B_ 2
#define N_ 9
#define CB_ 80
#define H_ 120
#define W_ 160
#define D_ 64
#define P_ 80000
#define HW_ (H_*W_)        // 19200
#define NPIX_ (B_*N_*HW_)  // 345600
#define NEG_ (-10000.0f)

using short8 = __attribute__((ext_vector_type(8))) short;
using f32x4  = __attribute__((ext_vector_type(4))) float;

static __device__ __forceinline__ float bflo(uint32_t u) {
    return __uint_as_float(u << 16);
}
static __device__ __forceinline__ float bfhi(uint32_t u) {
    return __uint_as_float(u & 0xffff0000u);
}
// RNE float->bf16 bits
static __device__ __forceinline__ uint32_t f2bf_bits(float f) {
    uint32_t u = __float_as_uint(f);
    return (u + 0x7fffu + ((u >> 16) & 1u)) >> 16;
}
static __device__ __forceinline__ uint32_t packbf(float a, float b) {
    return f2bf_bits(a) | (f2bf_bits(b) << 16);
}

// ---------------------------------------------------------------------------
// Kernel 1: key_maps for BOTH sets via MFMA.
//   km[pix][d] dword = (set1 bf16 lo, set2 bf16 hi)
// Block: 4 waves, tile 128 px x 64 d x 2 sets, K=80 padded to 96.
// Wave: 64 px x 32 d x both sets = 16 mfma_16x16x32 per K-chunk, 8 ds_read_b128.
// ---------------------------------------------------------------------------
__global__ __launch_bounds__(256) void keymap_mfma_kernel(
    const float* __restrict__ img,
    const float* __restrict__ Wk1, const float* __restrict__ bk1,
    const float* __restrict__ Wk2, const float* __restrict__ bk2,
    uint32_t* __restrict__ km)
{
    // row stride 104 bf16 = 208 B = 13*16 B: b128-aligned, balanced banks
    __shared__ short a_lds[128][104];   // a[px][k]   (bf16 bits)
    __shared__ short w_lds[128][104];   // w[s*64+d][k]
    const int tid = threadIdx.x;

    // stage weights transposed, zero-pad k in [80,96)
    for (int idx = tid; idx < 128 * 96; idx += 256) {
        int row = idx / 96;
        int k   = idx - row * 96;
        int s = row >> 6, d = row & 63;
        float v = 0.f;
        if (k < 80) v = s ? Wk2[d * 80 + k] : Wk1[d * 80 + k];
        w_lds[row][k] = (short)f2bf_bits(v);
    }

    // stage A tile: a[px][c] = bf16(img[bn][c][hw0+px]), zero-pad c in [80,96)
    const int pix0 = blockIdx.x * 128;
    const int bn   = pix0 / HW_;
    const int hw0  = pix0 - bn * HW_;
    const float* ibase = img + (size_t)bn * CB_ * HW_ + hw0;
    {
        const int px = tid & 127;
        const int c0 = tid >> 7;          // 0 or 1
        for (int cc = 0; cc < 96; cc += 2) {
            int c = cc + c0;
            float v = (c < 80) ? ibase[c * HW_ + px] : 0.f;
            a_lds[px][c] = (short)f2bf_bits(v);
        }
    }
    __syncthreads();

    const int lane = tid & 63;
    const int wv   = tid >> 6;
    const int pxw  = (wv & 1) * 64;      // wave's pixel half
    const int dw   = (wv >> 1) * 32;     // wave's d half
    const int lr   = lane & 15;
    const int lg   = lane >> 4;

    f32x4 acc1[4][2], acc2[4][2];
    #pragma unroll
    for (int mi = 0; mi < 4; mi++)
        #pragma unroll
        for (int ni = 0; ni < 2; ni++) {
            acc1[mi][ni] = (f32x4){0.f, 0.f, 0.f, 0.f};
            acc2[mi][ni] = (f32x4){0.f, 0.f, 0.f, 0.f};
        }

    #pragma unroll
    for (int kc = 0; kc < 3; kc++) {
        const int k0 = kc * 32;
        short8 av[4], bv1[2], bv2[2];
        #pragma unroll
        for (int mi = 0; mi < 4; mi++)
            av[mi] = *reinterpret_cast<const short8*>(&a_lds[pxw + mi * 16 + lr][k0 + lg * 8]);
        #pragma unroll
        for (int ni = 0; ni < 2; ni++) {
            bv1[ni] = *reinterpret_cast<const short8*>(&w_lds[dw + ni * 16 + lr][k0 + lg * 8]);
            bv2[ni] = *reinterpret_cast<const short8*>(&w_lds[64 + dw + ni * 16 + lr][k0 + lg * 8]);
        }
        #pragma unroll
        for (int mi = 0; mi < 4; mi++) {
            #pragma unroll
            for (int ni = 0; ni < 2; ni++) {
                acc1[mi][ni] = __builtin_amdgcn_mfma_f32_16x16x32_bf16(av[mi], bv1[ni], acc1[mi][ni], 0, 0, 0);
                acc2[mi][ni] = __builtin_amdgcn_mfma_f32_16x16x32_bf16(av[mi], bv2[ni], acc2[mi][ni], 0, 0, 0);
            }
        }
    }

    // epilogue: add bias, pack (set1,set2) -> one dword, coalesced stores
    #pragma unroll
    for (int ni = 0; ni < 2; ni++) {
        const int d = dw + ni * 16 + lr;
        const float b1 = bk1[d], b2 = bk2[d];
        #pragma unroll
        for (int mi = 0; mi < 4; mi++) {
            #pragma unroll
            for (int r = 0; r < 4; r++) {
                int pix = pix0 + pxw + mi * 16 + lg * 4 + r;
                km[(size_t)pix * 64 + d] = packbf(acc1[mi][ni][r] + b1, acc2[mi][ni][r] + b2);
            }
        }
    }
}

// ---------------------------------------------------------------------------
// Kernel 1b: q1 prepass + out-init.  (unchanged)
//   q1s[p][d] = 0.125 * (Wq1 . vf[p] + bq1); out[p] = vf[p]
// ---------------------------------------------------------------------------
__global__ __launch_bounds__(256) void qinit_kernel(
    const float* __restrict__ vfeat,
    const float* __restrict__ Wq1, const float* __restrict__ bq1,
    float* __restrict__ q1s, float* __restrict__ out)
{
    __shared__ float wt_lds[64][68];   // wt[c][d] = Wq1[d][c], padded
    __shared__ float vf_lds[64][68];
    __shared__ float bq_lds[64];
    const int tid = threadIdx.x;

    for (int idx = tid; idx < 4096; idx += 256) {
        int d = idx >> 6, c = idx & 63;
        wt_lds[c][d] = Wq1[idx];
    }
    if (tid < 64) bq_lds[tid] = bq1[tid];

    const int pt0 = blockIdx.x * 64;
    const float4* vf4 = reinterpret_cast<const float4*>(vfeat + (size_t)pt0 * 64);
    float4* out4 = reinterpret_cast<float4*>(out + (size_t)pt0 * 64);
    for (int idx = tid; idx < 1024; idx += 256) {
        float4 v = vf4[idx];
        out4[idx] = v;
        int r = idx >> 4, c4 = (idx & 15) * 4;
        *reinterpret_cast<float4*>(&vf_lds[r][c4]) = v;
    }
    __syncthreads();

    const int pl = tid >> 2;
    const int d0 = (tid & 3) * 16;
    float acc[16];
    #pragma unroll
    for (int i = 0; i < 16; i++) acc[i] = bq_lds[d0 + i];
    for (int k = 0; k < 64; k++) {
        float a = vf_lds[pl][k];
        const float4* wr = reinterpret_cast<const float4*>(&wt_lds[k][d0]);
        float4 w0 = wr[0], w1 = wr[1], w2 = wr[2], w3 = wr[3];
        acc[0]  += a * w0.x; acc[1]  += a * w0.y; acc[2]  += a * w0.z; acc[3]  += a * w0.w;
        acc[4]  += a * w1.x; acc[5]  += a * w1.y; acc[6]  += a * w1.z; acc[7]  += a * w1.w;
        acc[8]  += a * w2.x; acc[9]  += a * w2.y; acc[10] += a * w2.z; acc[11] += a * w2.w;
        acc[12] += a * w3.x; acc[13] += a * w3.y; acc[14] += a * w3.z; acc[15] += a * w3.w;
    }
    float4* q4 = reinterpret_cast<float4*>(q1s + (size_t)(pt0 + pl) * 64 + d0);
    #pragma unroll
    for (int j = 0; j < 4; j++) {
        q4[j] = make_float4(acc[4*j] * 0.125f, acc[4*j+1] * 0.125f,
                            acc[4*j+2] * 0.125f, acc[4*j+3] * 0.125f);
    }
}

// ---------------------------------------------------------------------------
// Kernel 2: persistent-wave attention, SEL-ONLY.  (unchanged)
// ---------------------------------------------------------------------------
__global__ __launch_bounds__(256) void attn_kernel(
    const uint32_t* __restrict__ km,
    const int*   __restrict__ coords,
    const float* __restrict__ vfeat,
    const float* __restrict__ proj,
    const float* __restrict__ origins,
    const int*   __restrict__ cmask,
    const float* __restrict__ q1s,
    const float* __restrict__ Wq2, const float* __restrict__ bq2,
    float* __restrict__ out)
{
    __shared__ __align__(16) float wq_lds[64 * 66];
    __shared__ __align__(16) float f_lds[4 * 64];
    __shared__ float bq_lds[64];
    __shared__ float proj_lds[B_ * N_ * 12];   // 216
    const int tid = threadIdx.x;

    for (int idx = tid; idx < 4096; idx += 256) {
        int d = idx >> 6, c = idx & 63;
        wq_lds[d * 66 + c] = Wq2[idx];
    }
    if (tid < 64) bq_lds[tid] = bq2[tid];
    if (tid < B_ * N_ * 12) proj_lds[tid] = proj[tid];
    __syncthreads();

    const int lane = tid & 63;
    const int wid  = tid >> 6;
    const int nw   = gridDim.x * 4;

    const float o0x = origins[0], o0y = origins[1], o0z = origins[2];
    const float o1x = origins[3], o1y = origins[4], o1z = origins[5];

    const int4* coords4 = reinterpret_cast<const int4*>(coords);

    int p = blockIdx.x * 4 + wid;
    int4 cv  = coords4[p];
    int  cmv = cmask[p];

    while (true) {
        const int pn = p + nw;
        const bool have_next = pn < P_;
        int4 cv_n; int cm_n = 0;
        if (have_next) {
            cv_n = coords4[pn];
            cm_n = cmask[pn];
        }

        if (cmv > 1) {
            const float vf = vfeat[(size_t)p * 64 + lane];
            const float q1 = q1s[(size_t)p * 64 + lane];   // pre-scaled

            const int  bi   = cv.w;
            const float wldx = (float)cv.x * 0.16f + (bi ? o1x : o0x);
            const float wldy = (float)cv.y * 0.16f + (bi ? o1y : o0y);
            const float wldz = (float)cv.z * 0.16f + (bi ? o1z : o0z);

            int packw = -1; float fx = 0.f, fy = 0.f;
            if (lane < N_) {
                const float* Pr = &proj_lds[(bi * N_ + lane) * 12];
                float c0 = Pr[0]*wldx + Pr[1]*wldy + Pr[2]*wldz  + Pr[3];
                float c1 = Pr[4]*wldx + Pr[5]*wldy + Pr[6]*wldz  + Pr[7];
                float c2 = Pr[8]*wldx + Pr[9]*wldy + Pr[10]*wldz + Pr[11];
                float gx = 2.f * (c0 / c2) / (float)(W_ - 1) - 1.f;
                float gy = 2.f * (c1 / c2) / (float)(H_ - 1) - 1.f;
                if (fabsf(gx) <= 1.f && fabsf(gy) <= 1.f && c2 > 0.f) {
                    float px = (gx + 1.f) * 0.5f * (float)(W_ - 1);
                    float py = (gy + 1.f) * 0.5f * (float)(H_ - 1);
                    float x0 = floorf(px), y0 = floorf(py);
                    fx = px - x0; fy = py - y0;
                    int x0i = (int)x0, y0i = (int)y0;
                    int pb = ((bi * N_ + lane) * H_ + y0i) * W_ + x0i;
                    packw = pb | ((x0i < W_ - 1) ? (1 << 20) : 0)
                               | ((y0i < H_ - 1) ? (1 << 21) : 0);
                }
            }

            int   pwv[N_];
            float kf1[N_], kf2[N_];
            #pragma unroll
            for (int n = 0; n < N_; n++) pwv[n] = __shfl(packw, n);

            #pragma unroll
            for (int n = 0; n < N_; n++) {
                kf1[n] = 0.f; kf2[n] = 0.f;
                int pw = pwv[n];
                if (pw >= 0) {
                    float wx = __shfl(fx, n), wy = __shfl(fy, n);
                    int pb  = pw & 0xFFFFF;
                    int dxo = (pw & (1 << 20)) ? 64 : 0;
                    int dyo = (pw & (1 << 21)) ? (W_ * 64) : 0;
                    const uint32_t* kb = km + (size_t)pb * 64 + lane;
                    uint32_t u00 = kb[0];
                    uint32_t u01 = kb[dxo];
                    uint32_t u10 = kb[dyo];
                    uint32_t u11 = kb[dyo + dxo];
                    float w11 = wx * wy;
                    float w01 = wx - w11;
                    float w10 = wy - w11;
                    float w00 = 1.f - wx - wy + w11;
                    kf1[n] = w00*bflo(u00) + w01*bflo(u01) + w10*bflo(u10) + w11*bflo(u11);
                    kf2[n] = w00*bfhi(u00) + w01*bfhi(u01) + w10*bfhi(u10) + w11*bfhi(u11);
                }
            }

            float l1[N_];
            #pragma unroll
            for (int n = 0; n < N_; n++) {
                float t = q1 * kf1[n];
                #pragma unroll
                for (int off = 32; off >= 1; off >>= 1) t += __shfl_xor(t, off);
                l1[n] = (pwv[n] >= 0) ? t : NEG_;
            }
            float mx = l1[0];
            #pragma unroll
            for (int n = 1; n < N_; n++) mx = fmaxf(mx, l1[n]);
            float ssum = 0.f, pr[N_];
            #pragma unroll
            for (int n = 0; n < N_; n++) { pr[n] = __expf(l1[n] - mx); ssum += pr[n]; }
            float inv = 1.f / ssum;
            float y1 = 0.f;
            #pragma unroll
            for (int n = 0; n < N_; n++) y1 += pr[n] * kf1[n];
            const float fcur = vf + y1 * inv;

            f_lds[wid * 64 + lane] = fcur;
            float q2 = bq_lds[lane];
            {
                const float2* wrow = reinterpret_cast<const float2*>(&wq_lds[lane * 66]);
                const float2* fv   = reinterpret_cast<const float2*>(&f_lds[wid * 64]);
                #pragma unroll 8
                for (int cc = 0; cc < 32; cc++) {
                    float2 w = wrow[cc]; float2 v = fv[cc];
                    q2 += w.x * v.x + w.y * v.y;
                }
            }
            q2 *= 0.125f;

            float l2[N_];
            #pragma unroll
            for (int n = 0; n < N_; n++) {
                float t = q2 * kf2[n];
                #pragma unroll
                for (int off = 32; off >= 1; off >>= 1) t += __shfl_xor(t, off);
                l2[n] = (pwv[n] >= 0) ? t : NEG_;
            }
            float mx2 = l2[0];
            #pragma unroll
            for (int n = 1; n < N_; n++) mx2 = fmaxf(mx2, l2[n]);
            float ssum2 = 0.f, pr2[N_];
            #pragma unroll
            for (int n = 0; n < N_; n++) { pr2[n] = __expf(l2[n] - mx2); ssum2 += pr2[n]; }
            float inv2 = 1.f / ssum2;
            float y2 = 0.f;
            #pragma unroll
            for (int n = 0; n < N_; n++) y2 += pr2[n] * kf2[n];

            out[(size_t)p * 64 + lane] = fcur + y2 * inv2;
        }

        if (!have_next) break;
        p = pn; cv = cv_n; cmv = cm_n;
    }
}

extern "C" void kernel_launch(void* const* d_in, const int* in_sizes, int n_in,
                              void* d_out, int out_size, void* d_ws, size_t ws_size,
                              hipStream_t stream) {
    const float* img    = (const float*)d_in[0];
    const int*   coords = (const int*)  d_in[1];
    const float* vf     = (const float*)d_in[2];
    const float* proj   = (const float*)d_in[3];
    const float* org    = (const float*)d_in[4];
    const int*   cm     = (const int*)  d_in[5];
    const float* Wq1    = (const float*)d_in[6];
    const float* bq1    = (const float*)d_in[7];
    const float* Wk1    = (const float*)d_in[8];
    const float* bk1    = (const float*)d_in[9];
    const float* Wq2    = (const float*)d_in[10];
    const float* bq2    = (const float*)d_in[11];
    const float* Wk2    = (const float*)d_in[12];
    const float* bk2    = (const float*)d_in[13];

    uint32_t* km  = (uint32_t*)d_ws;                               // 88.5 MB
    float*    q1s = (float*)((char*)d_ws + (size_t)NPIX_ * 64 * 4); // 20.5 MB
    float*    o   = (float*)d_out;

    keymap_mfma_kernel<<<dim3(NPIX_ / 128), dim3(256), 0, stream>>>(img, Wk1, bk1, Wk2, bk2, km);
    qinit_kernel<<<dim3(P_ / 64), dim3(256), 0, stream>>>(vf, Wq1, bq1, q1s, o);
    attn_kernel<<<dim3(2048), dim3(256), 0, stream>>>(km, coords, vf, proj, org, cm,
                                                      q1s, Wq2, bq2, o);
}

// Round 9
// 185.706 us; speedup vs baseline: 3.4434x; 1.2378x over previous
//
#include <hip/hip_runtime.h>
#include <hip/hip_bf16.h>
#include <stdint.h>

#define B_ 2
#define N_ 9
#define CB_ 80
#define H_ 120
#define W_ 160
#define D_ 64
#define P_ 80000
#define HW_ (H_*W_)        // 19200
#define NPIX_ (B_*N_*HW_)  // 345600
#define NEG_ (-10000.0f)

using short8 = __attribute__((ext_vector_type(8))) short;
using f32x4  = __attribute__((ext_vector_type(4))) float;

static __device__ __forceinline__ float bflo(uint32_t u) {
    return __uint_as_float(u << 16);
}
static __device__ __forceinline__ float bfhi(uint32_t u) {
    return __uint_as_float(u & 0xffff0000u);
}
// RNE float->bf16 bits
static __device__ __forceinline__ uint32_t f2bf_bits(float f) {
    uint32_t u = __float_as_uint(f);
    return (u + 0x7fffu + ((u >> 16) & 1u)) >> 16;
}
static __device__ __forceinline__ uint32_t packbf(float a, float b) {
    return f2bf_bits(a) | (f2bf_bits(b) << 16);
}

// ---------------------------------------------------------------------------
// Kernel 1: key_maps for BOTH sets via MFMA.
//   km[pix][d] dword = (set1 bf16 lo, set2 bf16 hi)
// Block: 4 waves, tile 128 px x 64 d x 2 sets, K=80 padded to 96.
// v2: W fragments loaded straight to registers (no W LDS, no staging writes);
//     A staged with ds_write_b128 at the bank-floor pattern. LDS 26.6 KB.
// ---------------------------------------------------------------------------
__global__ __launch_bounds__(256) void keymap_mfma_kernel(
    const float* __restrict__ img,
    const float* __restrict__ Wk1, const float* __restrict__ bk1,
    const float* __restrict__ Wk2, const float* __restrict__ bk2,
    uint32_t* __restrict__ km)
{
    // row stride 104 bf16 = 208 B = 13*16 B: b128-aligned; rows 0..7 cover all
    // 32 banks exactly once -> b128 read/write at the bank floor
    __shared__ short a_lds[128][104];   // a[px][k] (bf16 bits), 26.6 KB
    const int tid  = threadIdx.x;
    const int lane = tid & 63;
    const int wv   = tid >> 6;
    const int lr   = lane & 15;
    const int lg   = lane >> 4;
    const int dw   = (wv >> 1) * 32;     // wave's d half
    const int pxw  = (wv & 1) * 64;      // wave's pixel half

    // ---- W fragments -> registers (8 consecutive floats per lane; L2-hot) ----
    short8 bf1[3][2], bf2[3][2];
    #pragma unroll
    for (int kc = 0; kc < 3; kc++) {
        const int k = kc * 32 + lg * 8;
        #pragma unroll
        for (int ni = 0; ni < 2; ni++) {
            const int d = dw + ni * 16 + lr;
            short8 v1 = {0,0,0,0,0,0,0,0}, v2 = {0,0,0,0,0,0,0,0};
            if (k < 80) {
                const float4* p1 = reinterpret_cast<const float4*>(Wk1 + d * 80 + k);
                const float4* p2 = reinterpret_cast<const float4*>(Wk2 + d * 80 + k);
                float4 a0 = p1[0], a1 = p1[1];
                float4 c0 = p2[0], c1 = p2[1];
                v1[0] = (short)f2bf_bits(a0.x); v1[1] = (short)f2bf_bits(a0.y);
                v1[2] = (short)f2bf_bits(a0.z); v1[3] = (short)f2bf_bits(a0.w);
                v1[4] = (short)f2bf_bits(a1.x); v1[5] = (short)f2bf_bits(a1.y);
                v1[6] = (short)f2bf_bits(a1.z); v1[7] = (short)f2bf_bits(a1.w);
                v2[0] = (short)f2bf_bits(c0.x); v2[1] = (short)f2bf_bits(c0.y);
                v2[2] = (short)f2bf_bits(c0.z); v2[3] = (short)f2bf_bits(c0.w);
                v2[4] = (short)f2bf_bits(c1.x); v2[5] = (short)f2bf_bits(c1.y);
                v2[6] = (short)f2bf_bits(c1.z); v2[7] = (short)f2bf_bits(c1.w);
            }
            bf1[kc][ni] = v1; bf2[kc][ni] = v2;
        }
    }

    // ---- A tile -> LDS: thread owns (px, k-octet); b128 writes ----
    const int pix0 = blockIdx.x * 128;
    const int bn   = pix0 / HW_;
    const int hw0  = pix0 - bn * HW_;
    const float* ibase = img + (size_t)bn * CB_ * HW_ + hw0;
    {
        const int px = tid & 127;
        const int kh = (tid >> 7) * 48;          // 0 or 48
        #pragma unroll
        for (int oct = 0; oct < 6; oct++) {
            const int k = kh + oct * 8;
            short8 v = {0,0,0,0,0,0,0,0};
            if (k < 80) {
                #pragma unroll
                for (int j = 0; j < 8; j++)
                    v[j] = (short)f2bf_bits(ibase[(k + j) * HW_ + px]);
            }
            *reinterpret_cast<short8*>(&a_lds[px][k]) = v;
        }
    }
    __syncthreads();

    f32x4 acc1[4][2], acc2[4][2];
    #pragma unroll
    for (int mi = 0; mi < 4; mi++)
        #pragma unroll
        for (int ni = 0; ni < 2; ni++) {
            acc1[mi][ni] = (f32x4){0.f, 0.f, 0.f, 0.f};
            acc2[mi][ni] = (f32x4){0.f, 0.f, 0.f, 0.f};
        }

    #pragma unroll
    for (int kc = 0; kc < 3; kc++) {
        const int k0 = kc * 32;
        short8 av[4];
        #pragma unroll
        for (int mi = 0; mi < 4; mi++)
            av[mi] = *reinterpret_cast<const short8*>(&a_lds[pxw + mi * 16 + lr][k0 + lg * 8]);
        #pragma unroll
        for (int mi = 0; mi < 4; mi++) {
            #pragma unroll
            for (int ni = 0; ni < 2; ni++) {
                acc1[mi][ni] = __builtin_amdgcn_mfma_f32_16x16x32_bf16(av[mi], bf1[kc][ni], acc1[mi][ni], 0, 0, 0);
                acc2[mi][ni] = __builtin_amdgcn_mfma_f32_16x16x32_bf16(av[mi], bf2[kc][ni], acc2[mi][ni], 0, 0, 0);
            }
        }
    }

    // epilogue: add bias, pack (set1,set2) -> one dword, coalesced stores
    #pragma unroll
    for (int ni = 0; ni < 2; ni++) {
        const int d = dw + ni * 16 + lr;
        const float b1 = bk1[d], b2 = bk2[d];
        #pragma unroll
        for (int mi = 0; mi < 4; mi++) {
            #pragma unroll
            for (int r = 0; r < 4; r++) {
                int pix = pix0 + pxw + mi * 16 + lg * 4 + r;
                km[(size_t)pix * 64 + d] = packbf(acc1[mi][ni][r] + b1, acc2[mi][ni][r] + b2);
            }
        }
    }
}

// ---------------------------------------------------------------------------
// Kernel 1b: q1 prepass + out-init.  (unchanged)
//   q1s[p][d] = 0.125 * (Wq1 . vf[p] + bq1); out[p] = vf[p]
// ---------------------------------------------------------------------------
__global__ __launch_bounds__(256) void qinit_kernel(
    const float* __restrict__ vfeat,
    const float* __restrict__ Wq1, const float* __restrict__ bq1,
    float* __restrict__ q1s, float* __restrict__ out)
{
    __shared__ float wt_lds[64][68];   // wt[c][d] = Wq1[d][c], padded
    __shared__ float vf_lds[64][68];
    __shared__ float bq_lds[64];
    const int tid = threadIdx.x;

    for (int idx = tid; idx < 4096; idx += 256) {
        int d = idx >> 6, c = idx & 63;
        wt_lds[c][d] = Wq1[idx];
    }
    if (tid < 64) bq_lds[tid] = bq1[tid];

    const int pt0 = blockIdx.x * 64;
    const float4* vf4 = reinterpret_cast<const float4*>(vfeat + (size_t)pt0 * 64);
    float4* out4 = reinterpret_cast<float4*>(out + (size_t)pt0 * 64);
    for (int idx = tid; idx < 1024; idx += 256) {
        float4 v = vf4[idx];
        out4[idx] = v;
        int r = idx >> 4, c4 = (idx & 15) * 4;
        *reinterpret_cast<float4*>(&vf_lds[r][c4]) = v;
    }
    __syncthreads();

    const int pl = tid >> 2;
    const int d0 = (tid & 3) * 16;
    float acc[16];
    #pragma unroll
    for (int i = 0; i < 16; i++) acc[i] = bq_lds[d0 + i];
    for (int k = 0; k < 64; k++) {
        float a = vf_lds[pl][k];
        const float4* wr = reinterpret_cast<const float4*>(&wt_lds[k][d0]);
        float4 w0 = wr[0], w1 = wr[1], w2 = wr[2], w3 = wr[3];
        acc[0]  += a * w0.x; acc[1]  += a * w0.y; acc[2]  += a * w0.z; acc[3]  += a * w0.w;
        acc[4]  += a * w1.x; acc[5]  += a * w1.y; acc[6]  += a * w1.z; acc[7]  += a * w1.w;
        acc[8]  += a * w2.x; acc[9]  += a * w2.y; acc[10] += a * w2.z; acc[11] += a * w2.w;
        acc[12] += a * w3.x; acc[13] += a * w3.y; acc[14] += a * w3.z; acc[15] += a * w3.w;
    }
    float4* q4 = reinterpret_cast<float4*>(q1s + (size_t)(pt0 + pl) * 64 + d0);
    #pragma unroll
    for (int j = 0; j < 4; j++) {
        q4[j] = make_float4(acc[4*j] * 0.125f, acc[4*j+1] * 0.125f,
                            acc[4*j+2] * 0.125f, acc[4*j+3] * 0.125f);
    }
}

// ---------------------------------------------------------------------------
// Kernel 2: persistent-wave attention, SEL-ONLY.  (unchanged)
// ---------------------------------------------------------------------------
__global__ __launch_bounds__(256) void attn_kernel(
    const uint32_t* __restrict__ km,
    const int*   __restrict__ coords,
    const float* __restrict__ vfeat,
    const float* __restrict__ proj,
    const float* __restrict__ origins,
    const int*   __restrict__ cmask,
    const float* __restrict__ q1s,
    const float* __restrict__ Wq2, const float* __restrict__ bq2,
    float* __restrict__ out)
{
    __shared__ __align__(16) float wq_lds[64 * 66];
    __shared__ __align__(16) float f_lds[4 * 64];
    __shared__ float bq_lds[64];
    __shared__ float proj_lds[B_ * N_ * 12];   // 216
    const int tid = threadIdx.x;

    for (int idx = tid; idx < 4096; idx += 256) {
        int d = idx >> 6, c = idx & 63;
        wq_lds[d * 66 + c] = Wq2[idx];
    }
    if (tid < 64) bq_lds[tid] = bq2[tid];
    if (tid < B_ * N_ * 12) proj_lds[tid] = proj[tid];
    __syncthreads();

    const int lane = tid & 63;
    const int wid  = tid >> 6;
    const int nw   = gridDim.x * 4;

    const float o0x = origins[0], o0y = origins[1], o0z = origins[2];
    const float o1x = origins[3], o1y = origins[4], o1z = origins[5];

    const int4* coords4 = reinterpret_cast<const int4*>(coords);

    int p = blockIdx.x * 4 + wid;
    int4 cv  = coords4[p];
    int  cmv = cmask[p];

    while (true) {
        const int pn = p + nw;
        const bool have_next = pn < P_;
        int4 cv_n; int cm_n = 0;
        if (have_next) {
            cv_n = coords4[pn];
            cm_n = cmask[pn];
        }

        if (cmv > 1) {
            const float vf = vfeat[(size_t)p * 64 + lane];
            const float q1 = q1s[(size_t)p * 64 + lane];   // pre-scaled

            const int  bi   = cv.w;
            const float wldx = (float)cv.x * 0.16f + (bi ? o1x : o0x);
            const float wldy = (float)cv.y * 0.16f + (bi ? o1y : o0y);
            const float wldz = (float)cv.z * 0.16f + (bi ? o1z : o0z);

            int packw = -1; float fx = 0.f, fy = 0.f;
            if (lane < N_) {
                const float* Pr = &proj_lds[(bi * N_ + lane) * 12];
                float c0 = Pr[0]*wldx + Pr[1]*wldy + Pr[2]*wldz  + Pr[3];
                float c1 = Pr[4]*wldx + Pr[5]*wldy + Pr[6]*wldz  + Pr[7];
                float c2 = Pr[8]*wldx + Pr[9]*wldy + Pr[10]*wldz + Pr[11];
                float gx = 2.f * (c0 / c2) / (float)(W_ - 1) - 1.f;
                float gy = 2.f * (c1 / c2) / (float)(H_ - 1) - 1.f;
                if (fabsf(gx) <= 1.f && fabsf(gy) <= 1.f && c2 > 0.f) {
                    float px = (gx + 1.f) * 0.5f * (float)(W_ - 1);
                    float py = (gy + 1.f) * 0.5f * (float)(H_ - 1);
                    float x0 = floorf(px), y0 = floorf(py);
                    fx = px - x0; fy = py - y0;
                    int x0i = (int)x0, y0i = (int)y0;
                    int pb = ((bi * N_ + lane) * H_ + y0i) * W_ + x0i;
                    packw = pb | ((x0i < W_ - 1) ? (1 << 20) : 0)
                               | ((y0i < H_ - 1) ? (1 << 21) : 0);
                }
            }

            int   pwv[N_];
            float kf1[N_], kf2[N_];
            #pragma unroll
            for (int n = 0; n < N_; n++) pwv[n] = __shfl(packw, n);

            #pragma unroll
            for (int n = 0; n < N_; n++) {
                kf1[n] = 0.f; kf2[n] = 0.f;
                int pw = pwv[n];
                if (pw >= 0) {
                    float wx = __shfl(fx, n), wy = __shfl(fy, n);
                    int pb  = pw & 0xFFFFF;
                    int dxo = (pw & (1 << 20)) ? 64 : 0;
                    int dyo = (pw & (1 << 21)) ? (W_ * 64) : 0;
                    const uint32_t* kb = km + (size_t)pb * 64 + lane;
                    uint32_t u00 = kb[0];
                    uint32_t u01 = kb[dxo];
                    uint32_t u10 = kb[dyo];
                    uint32_t u11 = kb[dyo + dxo];
                    float w11 = wx * wy;
                    float w01 = wx - w11;
                    float w10 = wy - w11;
                    float w00 = 1.f - wx - wy + w11;
                    kf1[n] = w00*bflo(u00) + w01*bflo(u01) + w10*bflo(u10) + w11*bflo(u11);
                    kf2[n] = w00*bfhi(u00) + w01*bfhi(u01) + w10*bfhi(u10) + w11*bfhi(u11);
                }
            }

            float l1[N_];
            #pragma unroll
            for (int n = 0; n < N_; n++) {
                float t = q1 * kf1[n];
                #pragma unroll
                for (int off = 32; off >= 1; off >>= 1) t += __shfl_xor(t, off);
                l1[n] = (pwv[n] >= 0) ? t : NEG_;
            }
            float mx = l1[0];
            #pragma unroll
            for (int n = 1; n < N_; n++) mx = fmaxf(mx, l1[n]);
            float ssum = 0.f, pr[N_];
            #pragma unroll
            for (int n = 0; n < N_; n++) { pr[n] = __expf(l1[n] - mx); ssum += pr[n]; }
            float inv = 1.f / ssum;
            float y1 = 0.f;
            #pragma unroll
            for (int n = 0; n < N_; n++) y1 += pr[n] * kf1[n];
            const float fcur = vf + y1 * inv;

            f_lds[wid * 64 + lane] = fcur;
            float q2 = bq_lds[lane];
            {
                const float2* wrow = reinterpret_cast<const float2*>(&wq_lds[lane * 66]);
                const float2* fv   = reinterpret_cast<const float2*>(&f_lds[wid * 64]);
                #pragma unroll 8
                for (int cc = 0; cc < 32; cc++) {
                    float2 w = wrow[cc]; float2 v = fv[cc];
                    q2 += w.x * v.x + w.y * v.y;
                }
            }
            q2 *= 0.125f;

            float l2[N_];
            #pragma unroll
            for (int n = 0; n < N_; n++) {
                float t = q2 * kf2[n];
                #pragma unroll
                for (int off = 32; off >= 1; off >>= 1) t += __shfl_xor(t, off);
                l2[n] = (pwv[n] >= 0) ? t : NEG_;
            }
            float mx2 = l2[0];
            #pragma unroll
            for (int n = 1; n < N_; n++) mx2 = fmaxf(mx2, l2[n]);
            float ssum2 = 0.f, pr2[N_];
            #pragma unroll
            for (int n = 0; n < N_; n++) { pr2[n] = __expf(l2[n] - mx2); ssum2 += pr2[n]; }
            float inv2 = 1.f / ssum2;
            float y2 = 0.f;
            #pragma unroll
            for (int n = 0; n < N_; n++) y2 += pr2[n] * kf2[n];

            out[(size_t)p * 64 + lane] = fcur + y2 * inv2;
        }

        if (!have_next) break;
        p = pn; cv = cv_n; cmv = cm_n;
    }
}

extern "C" void kernel_launch(void* const* d_in, const int* in_sizes, int n_in,
                              void* d_out, int out_size, void* d_ws, size_t ws_size,
                              hipStream_t stream) {
    const float* img    = (const float*)d_in[0];
    const int*   coords = (const int*)  d_in[1];
    const float* vf     = (const float*)d_in[2];
    const float* proj   = (const float*)d_in[3];
    const float* org    = (const float*)d_in[4];
    const int*   cm     = (const int*)  d_in[5];
    const float* Wq1    = (const float*)d_in[6];
    const float* bq1    = (const float*)d_in[7];
    const float* Wk1    = (const float*)d_in[8];
    const float* bk1    = (const float*)d_in[9];
    const float* Wq2    = (const float*)d_in[10];
    const float* bq2    = (const float*)d_in[11];
    const float* Wk2    = (const float*)d_in[12];
    const float* bk2    = (const float*)d_in[13];

    uint32_t* km  = (uint32_t*)d_ws;                               // 88.5 MB
    float*    q1s = (float*)((char*)d_ws + (size_t)NPIX_ * 64 * 4); // 20.5 MB
    float*    o   = (float*)d_out;

    keymap_mfma_kernel<<<dim3(NPIX_ / 128), dim3(256), 0, stream>>>(img, Wk1, bk1, Wk2, bk2, km);
    qinit_kernel<<<dim3(P_ / 64), dim3(256), 0, stream>>>(vf, Wq1, bq1, q1s, o);
    attn_kernel<<<dim3(2048), dim3(256), 0, stream>>>(km, coords, vf, proj, org, cm,
                                                      q1s, Wq2, bq2, o);
}